// Round 14
// baseline (105.047 us; speedup 1.0000x reference)
//
#include <hip/hip_runtime.h>
#include <hip/hip_bf16.h>
#include <cstdint>

typedef unsigned short u16;
typedef __attribute__((ext_vector_type(4))) float f32x4;
typedef __attribute__((ext_vector_type(8))) short s16x8;
typedef __attribute__((ext_vector_type(4))) unsigned int u32x4;

#define B_    2
#define LQ_   2048
#define LKV_  2048
#define H_    16
// softmax scale folded into Q at GEMM epilogue: 0.125 * log2(e)
#define QSCALE_ 0.18033688011112042f

__device__ __forceinline__ u16 f2b(float f) {
  union { float f; unsigned int u; } v; v.f = f;
  unsigned int r = v.u + 0x7fffu + ((v.u >> 16) & 1u);
  return (u16)(r >> 16);
}

__device__ __forceinline__ unsigned cvtpk(float lo, float hi) {
  unsigned r;
  asm("v_cvt_pk_bf16_f32 %0, %1, %2" : "=v"(r) : "v"(lo), "v"(hi));
  return r;
}

#if __has_builtin(__builtin_amdgcn_exp2f)
__device__ __forceinline__ float fexp2(float x) { return __builtin_amdgcn_exp2f(x); }
#else
__device__ __forceinline__ float fexp2(float x) {
  float r; asm volatile("v_exp_f32 %0, %1" : "=v"(r) : "v"(x)); return r;
}
#endif

#define GLOAD(g, l) __builtin_amdgcn_global_load_lds( \
    (const __attribute__((address_space(1))) void*)(g), \
    (__attribute__((address_space(3))) void*)(l), 16, 0, 0)

// ---------------- prep: fused input casts + weight transposes ----------------
__global__ void prep(const float* __restrict__ x, u16* __restrict__ xb,
                     const float* __restrict__ y, u16* __restrict__ yb,
                     const float* __restrict__ Wq, u16* __restrict__ WqT,
                     const float* __restrict__ Wkv, u16* __restrict__ WkvT,
                     const float* __restrict__ Wp, u16* __restrict__ WpT) {
  __shared__ u16 tile[64][65];
  const int bid = blockIdx.x;
  const int t = threadIdx.x;
  if (bid < 7168) {
    const float* in; u16* out; int i;
    if (bid < 4096) { in = x; out = xb; i = (bid * 256 + t) * 4; }
    else            { in = y; out = yb; i = ((bid - 4096) * 256 + t) * 4; }
    float4 v = *reinterpret_cast<const float4*>(in + i);
    ushort4 r;
    r.x = f2b(v.x); r.y = f2b(v.y); r.z = f2b(v.z); r.w = f2b(v.w);
    *reinterpret_cast<ushort4*>(out + i) = r;
    return;
  }
  const int tb = bid - 7168;
  const float* W; u16* WT; int K, N, bx, by;
  if (tb < 256)      { W = Wq;  WT = WqT;  K = 1024; N = 1024; bx = tb & 15;         by = tb >> 4; }
  else if (tb < 640) { W = Wkv; WT = WkvT; K = 768;  N = 2048; bx = (tb - 256) & 31; by = (tb - 256) >> 5; }
  else               { W = Wp;  WT = WpT;  K = 1024; N = 1024; bx = (tb - 640) & 15; by = (tb - 640) >> 4; }
  const int n0 = bx * 64, k0 = by * 64;
#pragma unroll
  for (int p = 0; p < 4; ++p) {
    int r = (t >> 4) + p * 16;
    int c = (t & 15) * 4;
    float4 v = *reinterpret_cast<const float4*>(W + (size_t)(k0 + r) * N + n0 + c);
    tile[r][c + 0] = f2b(v.x);
    tile[r][c + 1] = f2b(v.y);
    tile[r][c + 2] = f2b(v.z);
    tile[r][c + 3] = f2b(v.w);
  }
  __syncthreads();
#pragma unroll
  for (int p = 0; p < 4; ++p) {
    int nr = (t >> 4) + p * 16;
    int kc = (t & 15) * 4;
    ushort4 o;
    o.x = tile[kc + 0][nr];
    o.y = tile[kc + 1][nr];
    o.z = tile[kc + 2][nr];
    o.w = tile[kc + 3][nr];
    *reinterpret_cast<ushort4*>(WT + (size_t)(n0 + nr) * K + k0 + kc) = o;
  }
}

// ---------------- GEMM v5 (qkv): 128x128 tile, BK=32, dbuf, 1 barrier/step ----------------
// 4 waves = 2(wm) x 2(wn); wave-tile 64x64 (acc 4x4). LDS rows 64B (4 chunks),
// chunk swizzle c ^= (row>>1)&3 (min bank aliasing). Staging: thread t -> row t>>2,
// source chunk (t&3)^((t>>3)&3); dest = wave-base + lane*16 (linear, coalesced
// 64B per 4 lanes). Per step/wave: 4 GLOAD, 8 ds_read, 16 MFMA.
// OM==2: KV split (K compact / V transposed); OM==3: bf16 * QSCALE_.
template <int OM>
__device__ __forceinline__ void gemm_v5(
    const u16* __restrict__ A, const u16* __restrict__ BT,
    u16* __restrict__ Cb, u16* __restrict__ VTp,
    int N, int K, int m0, int n0, char* smem) {
  const int tid = threadIdx.x;
  const int w = tid >> 6, lane = tid & 63;
  const int l16 = lane & 15, lk = lane >> 4;
  const int wm = w >> 1, wn = w & 1;
  const int NS = K >> 5;

  f32x4 acc[4][4];
#pragma unroll
  for (int i = 0; i < 4; ++i)
#pragma unroll
    for (int j = 0; j < 4; ++j)
      acc[i][j] = (f32x4){0.f, 0.f, 0.f, 0.f};

  const int srow = tid >> 2;                           // 0..63
  const int sce = ((tid & 3) ^ ((tid >> 3) & 3)) * 8;  // pre-swizzled source elem offset
  const u16* gA = A + (size_t)(m0 + srow) * K + sce;
  const u16* gB = BT + (size_t)(n0 + srow) * K + sce;
  const size_t rstep = (size_t)64 * K;
  char* dA = smem + w * 1024;            // + bb*8192 + i*4096
  char* dB = smem + 16384 + w * 1024;

  auto stage = [&](int k0, int bb) {
    GLOAD(gA + k0,         dA + bb * 8192);
    GLOAD(gA + k0 + rstep, dA + bb * 8192 + 4096);
    GLOAD(gB + k0,         dB + bb * 8192);
    GLOAD(gB + k0 + rstep, dB + bb * 8192 + 4096);
  };

  const int swl = ((l16 >> 1) & 3) << 4;   // lane-constant read swizzle

  stage(0, 0);
  __syncthreads();
  int cur = 0;
  for (int s = 0; s < NS; ++s) {
    if (s + 1 < NS) stage((s + 1) * 32, cur ^ 1);
    const char* sAb = smem + cur * 8192;
    const char* sBb = smem + 16384 + cur * 8192;
    s16x8 af[4], bf[4];
#pragma unroll
    for (int mt = 0; mt < 4; ++mt)
      af[mt] = *reinterpret_cast<const s16x8*>(
          sAb + (wm * 64 + mt * 16 + l16) * 64 + ((lk * 16) ^ swl));
#pragma unroll
    for (int nt = 0; nt < 4; ++nt)
      bf[nt] = *reinterpret_cast<const s16x8*>(
          sBb + (wn * 64 + nt * 16 + l16) * 64 + ((lk * 16) ^ swl));
    __builtin_amdgcn_s_setprio(1);
#pragma unroll
    for (int mt = 0; mt < 4; ++mt)
#pragma unroll
      for (int nt = 0; nt < 4; ++nt)
        acc[mt][nt] = __builtin_amdgcn_mfma_f32_16x16x32_bf16(af[mt], bf[nt], acc[mt][nt], 0, 0, 0);
    __builtin_amdgcn_s_setprio(0);
    __syncthreads();
    cur ^= 1;
  }

#pragma unroll
  for (int mt = 0; mt < 4; ++mt) {
#pragma unroll
    for (int nt = 0; nt < 4; ++nt) {
      const int col = n0 + wn * 64 + nt * 16 + l16;
      const int row0 = m0 + wm * 64 + mt * 16 + lk * 4;
      if (OM == 2 && col >= 1024) {
        int b = row0 >> 11, kv = row0 & 2047;
        int h = (col >> 6) & 15, d = col & 63;
        ushort4 o;
        o.x = f2b(acc[mt][nt][0]); o.y = f2b(acc[mt][nt][1]);
        o.z = f2b(acc[mt][nt][2]); o.w = f2b(acc[mt][nt][3]);
        *reinterpret_cast<ushort4*>(VTp + (((size_t)(b * 16 + h) * 64 + d) * 2048 + kv)) = o;
      } else {
#pragma unroll
        for (int j = 0; j < 4; ++j) {
          int row = row0 + j;
          if (OM == 3) Cb[(size_t)row * N + col] = f2b(acc[mt][nt][j] * QSCALE_);
          else         Cb[(size_t)row * 1024 + col] = f2b(acc[mt][nt][j]);
        }
      }
    }
  }
}

// Q (256 blocks) + KV (512 blocks). All 768 blocks are resident at once
// (3/CU), so the Q/KV mix must be homogeneous PER CU, not just per XCD:
// within each XCD's 96-block sequence interleave [Q, KV, KV] (period 3).
// XCD x keeps Wq panel x and Wkv panels 2x,2x+1 L2-resident.
__global__ __launch_bounds__(256, 3)
void gemm_qkv(const u16* __restrict__ xb, const u16* __restrict__ WqT,
              const u16* __restrict__ yb, const u16* __restrict__ WkvT,
              u16* __restrict__ Qb, u16* __restrict__ Kbf, u16* __restrict__ VTb) {
  __shared__ __attribute__((aligned(16))) char smem[32768];
  const int bid = blockIdx.x;
  const int x = bid & 7, i = bid >> 3;   // 768 = 8 XCDs x 96
  const int i3 = i / 3;
  if (i - i3 * 3 == 0) {
    const int q = x * 32 + i3;           // n-tile = x (q>>5), m-tile = q&31
    gemm_v5<3>(xb, WqT, Qb, nullptr, 1024, 1024, (q & 31) * 128, (q >> 5) * 128, smem);
  } else {
    const int k = x * 64 + (i - i3 - 1); // n-tiles 2x..2x+1, m = k&31
    gemm_v5<2>(yb, WkvT, Kbf, VTb, 2048, 768, (k & 31) * 128, (k >> 5) * 128, smem);
  }
}

// ---------------- GEMM v4 core (proj, r10-exact): 128x64, BK=64, dbuf ----------------
__device__ __forceinline__ void gemm_core(
    int OM, const u16* __restrict__ A, const u16* __restrict__ BT,
    u16* __restrict__ Cb, float* __restrict__ Cf,
    const float* __restrict__ bias, u16* __restrict__ VTp,
    int N, int K, int m0, int n0, char* smem) {
  const int tid = threadIdx.x;
  const int w = tid >> 6, lane = tid & 63;
  const int l16 = lane & 15, lk = lane >> 4;
  const int wm = w >> 1, wn = w & 1;
  const int NS = K >> 6;

  f32x4 acc[4][2];
#pragma unroll
  for (int i = 0; i < 4; ++i)
#pragma unroll
    for (int j = 0; j < 2; ++j)
      acc[i][j] = (f32x4){0.f, 0.f, 0.f, 0.f};

  const int srow = tid >> 3;
  const int sck = (tid & 7) ^ (srow & 7);
  const u16* gA = A + (size_t)(m0 + srow) * K + sck * 8;
  const u16* gB = BT + (size_t)(n0 + srow) * K + sck * 8;
  char* dA = smem + w * 1024;
  char* dB = smem + 32768 + w * 1024;

  auto stage = [&](int k0, int bb) {
#pragma unroll
    for (int i = 0; i < 4; ++i)
      GLOAD(gA + (size_t)i * 32 * K + k0, dA + bb * 16384 + i * 4096);
#pragma unroll
    for (int i = 0; i < 2; ++i)
      GLOAD(gB + (size_t)i * 32 * K + k0, dB + bb * 8192 + i * 4096);
  };

  const int swa = (l16 & 7) << 4;

  stage(0, 0);
  __syncthreads();
  int cur = 0;
  for (int s = 0; s < NS; ++s) {
    if (s + 1 < NS) stage((s + 1) * 64, cur ^ 1);
    const char* sAb = smem + cur * 16384;
    const char* sBb = smem + 32768 + cur * 8192;
#pragma unroll
    for (int kk = 0; kk < 2; ++kk) {
      s16x8 af[4], bf[2];
#pragma unroll
      for (int mt = 0; mt < 4; ++mt)
        af[mt] = *reinterpret_cast<const s16x8*>(
            sAb + (wm * 64 + mt * 16 + l16) * 128 + ((kk * 64 + lk * 16) ^ swa));
#pragma unroll
      for (int nt = 0; nt < 2; ++nt)
        bf[nt] = *reinterpret_cast<const s16x8*>(
            sBb + (wn * 32 + nt * 16 + l16) * 128 + ((kk * 64 + lk * 16) ^ swa));
      __builtin_amdgcn_s_setprio(1);
#pragma unroll
      for (int mt = 0; mt < 4; ++mt)
#pragma unroll
        for (int nt = 0; nt < 2; ++nt)
          acc[mt][nt] = __builtin_amdgcn_mfma_f32_16x16x32_bf16(af[mt], bf[nt], acc[mt][nt], 0, 0, 0);
      __builtin_amdgcn_s_setprio(0);
    }
    __syncthreads();
    cur ^= 1;
  }

#pragma unroll
  for (int mt = 0; mt < 4; ++mt) {
#pragma unroll
    for (int nt = 0; nt < 2; ++nt) {
      const int col = n0 + wn * 32 + nt * 16 + l16;
      const int row0 = m0 + wm * 64 + mt * 16 + lk * 4;
#pragma unroll
      for (int j = 0; j < 4; ++j) {
        int row = row0 + j;
        Cf[(size_t)row * N + col] = acc[mt][nt][j] + bias[col];
      }
    }
  }
}

__global__ __launch_bounds__(256, 3)
void gemm_proj(const u16* __restrict__ Rb, const u16* __restrict__ WpT,
               float* __restrict__ out, const float* __restrict__ bias) {
  __shared__ __attribute__((aligned(16))) char smem[49152];
  const int bid = blockIdx.x;
  gemm_core(1, Rb, WpT, nullptr, out, bias, nullptr,
            1024, 1024, (bid & 31) * 128, (bid >> 5) * 64, smem);
}

// ---------------- flash attention v8 (unchanged -- measured good) ----------------
__global__ __launch_bounds__(512, 4)
void flash_attn(const u16* __restrict__ Kq, const u16* __restrict__ Qb,
                const u16* __restrict__ VT, u16* __restrict__ Rb) {
  __shared__ __attribute__((aligned(16))) char smem[65536];
  __shared__ float dmerge[512 * 2];

  const int tid = threadIdx.x;
  const int w = tid >> 6, l = tid & 63;
  const int l16 = l & 15, lk = l >> 4;
  const int half = w >> 2, w4 = w & 3;

  const int bid = blockIdx.x;
  const int wg = ((bid & 7) << 6) | (bid >> 3);
  const int qt = wg & 15, bh = wg >> 4;
  const int b = bh >> 4, h = bh & 15;
  const int qrow0 = qt * 128 + w4 * 32;

  const u16* qp = Qb + ((size_t)(b * LQ_ + qrow0 + l16)) * 1024 + h * 64;
  s16x8 qf[2][2];
#pragma unroll
  for (int g = 0; g < 2; ++g)
#pragma unroll
    for (int ksq = 0; ksq < 2; ++ksq)
      qf[g][ksq] = *reinterpret_cast<const s16x8*>(qp + g * 16 * 1024 + ksq * 32 + lk * 8);

  f32x4 Oacc[2][4], Osum[2];
#pragma unroll
  for (int g = 0; g < 2; ++g) {
    Osum[g] = (f32x4){0.f, 0.f, 0.f, 0.f};
#pragma unroll
    for (int dt = 0; dt < 4; ++dt) Oacc[g][dt] = (f32x4){0.f, 0.f, 0.f, 0.f};
  }

  const u16* Kg = Kq + ((size_t)(b * LKV_ + half * 1024)) * 1024 + h * 64;
  const u16* Vg = VT + ((size_t)bh * 64) * 2048 + half * 1024;
  char* Kl = smem + half * 32768;
  char* Vl = smem + half * 32768 + 16384;

  s16x8 ones;
#pragma unroll
  for (int i = 0; i < 8; ++i) ones[i] = (short)0x3F80;

  const int r0 = ((l16 >> 2) << 3) + (l16 & 3);
  const int swk = ((l16 & 3) | (((l16 >> 2) & 1) << 2)) << 4;
  const int swv = (l16 & 7) << 4;

  const int srow = (tid & 255) >> 3;
  const int sck = (tid & 7) ^ ((srow & 3) | (((srow >> 3) & 1) << 2));
  const int scv = (tid & 7) ^ (srow & 7);
  const u16* kp0 = Kg + (size_t)srow * 1024 + sck * 8;
  const u16* kp1 = kp0 + (size_t)32 * 1024;
  const u16* vp0 = Vg + (size_t)srow * 2048 + scv * 8;
  const u16* vp1 = vp0 + (size_t)32 * 2048;
  char* kd0 = Kl + w4 * 1024;
  char* vd0 = Vl + w4 * 1024;

  auto stage = [&](int bb) {
    GLOAD(kp0, kd0 + bb * 8192);
    GLOAD(kp1, kd0 + bb * 8192 + 4096);
    GLOAD(vp0, vd0 + bb * 8192);
    GLOAD(vp1, vd0 + bb * 8192 + 4096);
  };

  stage(0);
  kp0 += 65536; kp1 += 65536; vp0 += 64; vp1 += 64;
  __syncthreads();

  int cur = 0;
  for (int jt = 0; jt < 16; ++jt) {
    if (jt < 15) {
      stage(cur ^ 1);
      kp0 += 65536; kp1 += 65536; vp0 += 64; vp1 += 64;
    }
    const char* kb = Kl + cur * 8192;
    const char* vb = Vl + cur * 8192;

    f32x4 sacc[2][4];
#pragma unroll
    for (int g = 0; g < 2; ++g)
#pragma unroll
      for (int ct = 0; ct < 4; ++ct) sacc[g][ct] = (f32x4){0.f, 0.f, 0.f, 0.f};

    __builtin_amdgcn_s_setprio(1);
#pragma unroll
    for (int ct = 0; ct < 4; ++ct) {
      const int R = r0 + ((ct & 1) << 2) + ((ct >> 1) << 5);
      const char* rp = kb + R * 128;
      s16x8 ka0 = *reinterpret_cast<const s16x8*>(rp + ((lk * 16) ^ swk));
      s16x8 ka1 = *reinterpret_cast<const s16x8*>(rp + ((64 + lk * 16) ^ swk));
      sacc[0][ct] = __builtin_amdgcn_mfma_f32_16x16x32_bf16(ka0, qf[0][0], sacc[0][ct], 0, 0, 0);
      sacc[0][ct] = __builtin_amdgcn_mfma_f32_16x16x32_bf16(ka1, qf[0][1], sacc[0][ct], 0, 0, 0);
      sacc[1][ct] = __builtin_amdgcn_mfma_f32_16x16x32_bf16(ka0, qf[1][0], sacc[1][ct], 0, 0, 0);
      sacc[1][ct] = __builtin_amdgcn_mfma_f32_16x16x32_bf16(ka1, qf[1][1], sacc[1][ct], 0, 0, 0);
    }
    __builtin_amdgcn_s_setprio(0);

#pragma unroll
    for (int g = 0; g < 2; ++g)
#pragma unroll
      for (int ct = 0; ct < 4; ++ct)
#pragma unroll
        for (int j = 0; j < 4; ++j)
          sacc[g][ct][j] = fexp2(sacc[g][ct][j]);

#pragma unroll
    for (int f = 0; f < 2; ++f) {
      s16x8 va[4];
#pragma unroll
      for (int dt = 0; dt < 4; ++dt)
        va[dt] = *reinterpret_cast<const s16x8*>(vb + (dt * 16 + l16) * 128 + ((f * 64 + lk * 16) ^ swv));
      s16x8 pf[2];
#pragma unroll
      for (int g = 0; g < 2; ++g) {
        const f32x4 pA = sacc[g][2 * f];
        const f32x4 pB = sacc[g][2 * f + 1];
        union { unsigned u[4]; s16x8 v; } pk;
        pk.u[0] = cvtpk(pA[0], pA[1]);
        pk.u[1] = cvtpk(pA[2], pA[3]);
        pk.u[2] = cvtpk(pB[0], pB[1]);
        pk.u[3] = cvtpk(pB[2], pB[3]);
        pf[g] = pk.v;
      }
      __builtin_amdgcn_s_setprio(1);
#pragma unroll
      for (int dt = 0; dt < 4; ++dt) {
        Oacc[0][dt] = __builtin_amdgcn_mfma_f32_16x16x32_bf16(va[dt], pf[0], Oacc[0][dt], 0, 0, 0);
        Oacc[1][dt] = __builtin_amdgcn_mfma_f32_16x16x32_bf16(va[dt], pf[1], Oacc[1][dt], 0, 0, 0);
      }
      Osum[0] = __builtin_amdgcn_mfma_f32_16x16x32_bf16(ones, pf[0], Osum[0], 0, 0, 0);
      Osum[1] = __builtin_amdgcn_mfma_f32_16x16x32_bf16(ones, pf[1], Osum[1], 0, 0, 0);
      __builtin_amdgcn_s_setprio(0);
    }
    __syncthreads();
    cur ^= 1;
  }

  if (w >= 4) {
    char* mb = smem + (((w - 4) * 64 + l) * 128);
#pragma unroll
    for (int g = 0; g < 2; ++g)
#pragma unroll
      for (int dt = 0; dt < 4; ++dt)
        *reinterpret_cast<f32x4*>(mb + (((g * 4 + dt) * 16) ^ ((l & 7) << 4))) = Oacc[g][dt];
    dmerge[((w - 4) * 64 + l) * 2 + 0] = Osum[0][0];
    dmerge[((w - 4) * 64 + l) * 2 + 1] = Osum[1][0];
  }
  __syncthreads();
  if (w < 4) {
    const char* mb = smem + ((w * 64 + l) * 128);
#pragma unroll
    for (int g = 0; g < 2; ++g) {
      float inv = 1.f / (Osum[g][0] + dmerge[(w * 64 + l) * 2 + g]);
      u16* op = Rb + ((size_t)(b * LQ_ + qrow0 + g * 16 + l16)) * 1024 + h * 64 + lk * 4;
#pragma unroll
      for (int dt = 0; dt < 4; ++dt) {
        f32x4 o2 = *reinterpret_cast<const f32x4*>(mb + (((g * 4 + dt) * 16) ^ ((l & 7) << 4)));
        f32x4 s = Oacc[g][dt] + o2;
        ushort4 o;
        o.x = f2b(s[0] * inv); o.y = f2b(s[1] * inv);
        o.z = f2b(s[2] * inv); o.w = f2b(s[3] * inv);
        *reinterpret_cast<ushort4*>(op + dt * 16) = o;
      }
    }
  }
}

// ---------------- launch ----------------
extern "C" void kernel_launch(void* const* d_in, const int* in_sizes, int n_in,
                              void* d_out, int out_size, void* d_ws, size_t ws_size,
                              hipStream_t stream) {
  const float* x   = (const float*)d_in[0];
  const float* y   = (const float*)d_in[1];
  const float* Wq  = (const float*)d_in[2];
  const float* Wkv = (const float*)d_in[3];
  const float* Wp  = (const float*)d_in[4];
  const float* bp  = (const float*)d_in[5];
  float* out = (float*)d_out;

  u16* p = (u16*)d_ws;
  u16* xb   = p; p += (size_t)4096 * 1024;
  u16* yb   = p; p += (size_t)4096 * 768;
  u16* WqT  = p; p += (size_t)1024 * 1024;
  u16* WkvT = p; p += (size_t)2048 * 768;
  u16* WpT  = p; p += (size_t)1024 * 1024;
  u16* Qb   = p; p += (size_t)4096 * 1024;
  u16* Kbf  = p; p += (size_t)4096 * 1024;   // K compact [b*2048+kv][h*64+d]
  u16* VTb  = p; p += (size_t)4096 * 1024;   // [32][64][2048]
  u16* Rb   = p; p += (size_t)4096 * 1024;

  prep<<<8064, 256, 0, stream>>>(x, xb, y, yb, Wq, WqT, Wkv, WkvT, Wp, WpT);

  // Q = (x @ Wq)*QSCALE and KV = y @ Wkv (K -> Kbf, V -> VTb transposed), one launch
  gemm_qkv<<<768, 256, 0, stream>>>(xb, WqT, yb, WkvT, Qb, Kbf, VTb);
  // attention -> Rb [4096,1024] (halves merged in-block)
  flash_attn<<<512, 512, 0, stream>>>(Kbf, Qb, VTb, Rb);
  // out = Rb @ Wproj + bias : fp32 [4096,1024]
  gemm_proj<<<512, 256, 0, stream>>>(Rb, WpT, out, bp);
}

// Round 15
// 99.839 us; speedup vs baseline: 1.0522x; 1.0522x over previous
//
#include <hip/hip_runtime.h>
#include <hip/hip_bf16.h>
#include <cstdint>

typedef unsigned short u16;
typedef __attribute__((ext_vector_type(4))) float f32x4;
typedef __attribute__((ext_vector_type(8))) short s16x8;
typedef __attribute__((ext_vector_type(4))) unsigned int u32x4;

#define B_    2
#define LQ_   2048
#define LKV_  2048
#define H_    16
// softmax scale folded into Q at GEMM epilogue: 0.125 * log2(e)
#define QSCALE_ 0.18033688011112042f

__device__ __forceinline__ u16 f2b(float f) {
  union { float f; unsigned int u; } v; v.f = f;
  unsigned int r = v.u + 0x7fffu + ((v.u >> 16) & 1u);
  return (u16)(r >> 16);
}

__device__ __forceinline__ unsigned cvtpk(float lo, float hi) {
  unsigned r;
  asm("v_cvt_pk_bf16_f32 %0, %1, %2" : "=v"(r) : "v"(lo), "v"(hi));
  return r;
}

#if __has_builtin(__builtin_amdgcn_exp2f)
__device__ __forceinline__ float fexp2(float x) { return __builtin_amdgcn_exp2f(x); }
#else
__device__ __forceinline__ float fexp2(float x) {
  float r; asm volatile("v_exp_f32 %0, %1" : "=v"(r) : "v"(x)); return r;
}
#endif

#define GLOAD(g, l) __builtin_amdgcn_global_load_lds( \
    (const __attribute__((address_space(1))) void*)(g), \
    (__attribute__((address_space(3))) void*)(l), 16, 0, 0)

// ---------------- prep: fused input casts + weight transposes ----------------
__global__ void prep(const float* __restrict__ x, u16* __restrict__ xb,
                     const float* __restrict__ y, u16* __restrict__ yb,
                     const float* __restrict__ Wq, u16* __restrict__ WqT,
                     const float* __restrict__ Wkv, u16* __restrict__ WkvT,
                     const float* __restrict__ Wp, u16* __restrict__ WpT) {
  __shared__ u16 tile[64][65];
  const int bid = blockIdx.x;
  const int t = threadIdx.x;
  if (bid < 7168) {
    const float* in; u16* out; int i;
    if (bid < 4096) { in = x; out = xb; i = (bid * 256 + t) * 4; }
    else            { in = y; out = yb; i = ((bid - 4096) * 256 + t) * 4; }
    float4 v = *reinterpret_cast<const float4*>(in + i);
    ushort4 r;
    r.x = f2b(v.x); r.y = f2b(v.y); r.z = f2b(v.z); r.w = f2b(v.w);
    *reinterpret_cast<ushort4*>(out + i) = r;
    return;
  }
  const int tb = bid - 7168;
  const float* W; u16* WT; int K, N, bx, by;
  if (tb < 256)      { W = Wq;  WT = WqT;  K = 1024; N = 1024; bx = tb & 15;         by = tb >> 4; }
  else if (tb < 640) { W = Wkv; WT = WkvT; K = 768;  N = 2048; bx = (tb - 256) & 31; by = (tb - 256) >> 5; }
  else               { W = Wp;  WT = WpT;  K = 1024; N = 1024; bx = (tb - 640) & 15; by = (tb - 640) >> 4; }
  const int n0 = bx * 64, k0 = by * 64;
#pragma unroll
  for (int p = 0; p < 4; ++p) {
    int r = (t >> 4) + p * 16;
    int c = (t & 15) * 4;
    float4 v = *reinterpret_cast<const float4*>(W + (size_t)(k0 + r) * N + n0 + c);
    tile[r][c + 0] = f2b(v.x);
    tile[r][c + 1] = f2b(v.y);
    tile[r][c + 2] = f2b(v.z);
    tile[r][c + 3] = f2b(v.w);
  }
  __syncthreads();
#pragma unroll
  for (int p = 0; p < 4; ++p) {
    int nr = (t >> 4) + p * 16;
    int kc = (t & 15) * 4;
    ushort4 o;
    o.x = tile[kc + 0][nr];
    o.y = tile[kc + 1][nr];
    o.z = tile[kc + 2][nr];
    o.w = tile[kc + 3][nr];
    *reinterpret_cast<ushort4*>(WT + (size_t)(n0 + nr) * K + k0 + kc) = o;
  }
}

// ---------------- GEMM v4 core: 128x64 tile, BK=64, dbuf, 1 barrier/step ----------------
// 4 waves = 2(wm) x 2(wn); wave-tile 64x32; no split-K.
// LDS rows 128B, chunk swizzle (row&7) (8 distinct chunks per 8-lane phase: free).
// Staging: 8 consecutive threads cover one row's 128B (coalesced).
// Stage targets the other buffer -> single __syncthreads per step (32 MFMA/barrier).
// OM==1: fp32 out + bias; OM==2: KV split (K compact / V transposed); OM==3: bf16 * QSCALE_.
__device__ __forceinline__ void gemm_core(
    int OM, const u16* __restrict__ A, const u16* __restrict__ BT,
    u16* __restrict__ Cb, float* __restrict__ Cf,
    const float* __restrict__ bias, u16* __restrict__ VTp,
    int N, int K, int m0, int n0, char* smem) {
  const int tid = threadIdx.x;
  const int w = tid >> 6, lane = tid & 63;
  const int l16 = lane & 15, lk = lane >> 4;
  const int wm = w >> 1, wn = w & 1;
  const int NS = K >> 6;

  f32x4 acc[4][2];
#pragma unroll
  for (int i = 0; i < 4; ++i)
#pragma unroll
    for (int j = 0; j < 2; ++j)
      acc[i][j] = (f32x4){0.f, 0.f, 0.f, 0.f};

  // staging: row = tid>>3 (0..31) per round, chunk pre-XOR (row&7)
  const int srow = tid >> 3;
  const int sck = (tid & 7) ^ (srow & 7);
  const u16* gA = A + (size_t)(m0 + srow) * K + sck * 8;
  const u16* gB = BT + (size_t)(n0 + srow) * K + sck * 8;
  char* dA = smem + w * 1024;            // + bb*16384 + i*4096
  char* dB = smem + 32768 + w * 1024;    // + bb*8192 + i*4096

  auto stage = [&](int k0, int bb) {
#pragma unroll
    for (int i = 0; i < 4; ++i)
      GLOAD(gA + (size_t)i * 32 * K + k0, dA + bb * 16384 + i * 4096);
#pragma unroll
    for (int i = 0; i < 2; ++i)
      GLOAD(gB + (size_t)i * 32 * K + k0, dB + bb * 8192 + i * 4096);
  };

  const int swa = (l16 & 7) << 4;

  stage(0, 0);
  __syncthreads();
  int cur = 0;
  for (int s = 0; s < NS; ++s) {
    if (s + 1 < NS) stage((s + 1) * 64, cur ^ 1);
    const char* sAb = smem + cur * 16384;
    const char* sBb = smem + 32768 + cur * 8192;
#pragma unroll
    for (int kk = 0; kk < 2; ++kk) {
      s16x8 af[4], bf[2];
#pragma unroll
      for (int mt = 0; mt < 4; ++mt)
        af[mt] = *reinterpret_cast<const s16x8*>(
            sAb + (wm * 64 + mt * 16 + l16) * 128 + ((kk * 64 + lk * 16) ^ swa));
#pragma unroll
      for (int nt = 0; nt < 2; ++nt)
        bf[nt] = *reinterpret_cast<const s16x8*>(
            sBb + (wn * 32 + nt * 16 + l16) * 128 + ((kk * 64 + lk * 16) ^ swa));
      __builtin_amdgcn_s_setprio(1);
#pragma unroll
      for (int mt = 0; mt < 4; ++mt)
#pragma unroll
        for (int nt = 0; nt < 2; ++nt)
          acc[mt][nt] = __builtin_amdgcn_mfma_f32_16x16x32_bf16(af[mt], bf[nt], acc[mt][nt], 0, 0, 0);
      __builtin_amdgcn_s_setprio(0);
    }
    __syncthreads();
    cur ^= 1;
  }

#pragma unroll
  for (int mt = 0; mt < 4; ++mt) {
#pragma unroll
    for (int nt = 0; nt < 2; ++nt) {
      const int col = n0 + wn * 32 + nt * 16 + l16;
      const int row0 = m0 + wm * 64 + mt * 16 + lk * 4;
      if (OM == 2 && col >= 1024) {
        int b = row0 >> 11, kv = row0 & 2047;
        int h = (col >> 6) & 15, d = col & 63;
        ushort4 o;
        o.x = f2b(acc[mt][nt][0]); o.y = f2b(acc[mt][nt][1]);
        o.z = f2b(acc[mt][nt][2]); o.w = f2b(acc[mt][nt][3]);
        *reinterpret_cast<ushort4*>(VTp + (((size_t)(b * 16 + h) * 64 + d) * 2048 + kv)) = o;
      } else {
#pragma unroll
        for (int j = 0; j < 4; ++j) {
          int row = row0 + j;
          if (OM == 3)      Cb[(size_t)row * N + col] = f2b(acc[mt][nt][j] * QSCALE_);
          else if (OM == 2) Cb[(size_t)row * 1024 + col] = f2b(acc[mt][nt][j]);
          else              Cf[(size_t)row * N + col] = acc[mt][nt][j] + bias[col];
        }
      }
    }
  }
}

// Q-GEMM (blocks 0..511) + KV-GEMM (blocks 512..1535) in one launch (natural order:
// round-robin across XCDs mixes Q/KV homogeneously -- measured best, r10)
__global__ __launch_bounds__(256, 3)
void gemm_qkv(const u16* __restrict__ xb, const u16* __restrict__ WqT,
              const u16* __restrict__ yb, const u16* __restrict__ WkvT,
              u16* __restrict__ Qb, u16* __restrict__ Kbf, u16* __restrict__ VTb) {
  __shared__ __attribute__((aligned(16))) char smem[49152];
  const int bid = blockIdx.x;
  if (bid < 512) {
    gemm_core(3, xb, WqT, Qb, nullptr, nullptr, nullptr,
              1024, 1024, (bid & 31) * 128, (bid >> 5) * 64, smem);
  } else {
    const int t = bid - 512;
    gemm_core(2, yb, WkvT, Kbf, nullptr, nullptr, VTb,
              2048, 768, (t & 31) * 128, (t >> 5) * 64, smem);
  }
}

__global__ __launch_bounds__(256, 3)
void gemm_proj(const u16* __restrict__ Rb, const u16* __restrict__ WpT,
               float* __restrict__ out, const float* __restrict__ bias) {
  __shared__ __attribute__((aligned(16))) char smem[49152];
  const int bid = blockIdx.x;
  gemm_core(1, Rb, WpT, nullptr, out, bias, nullptr,
            1024, 1024, (bid & 31) * 128, (bid >> 5) * 64, smem);
}

// ---------------- flash attention v8 (unchanged -- measured good) ----------------
__global__ __launch_bounds__(512, 4)
void flash_attn(const u16* __restrict__ Kq, const u16* __restrict__ Qb,
                const u16* __restrict__ VT, u16* __restrict__ Rb) {
  __shared__ __attribute__((aligned(16))) char smem[65536];
  __shared__ float dmerge[512 * 2];

  const int tid = threadIdx.x;
  const int w = tid >> 6, l = tid & 63;
  const int l16 = l & 15, lk = l >> 4;
  const int half = w >> 2, w4 = w & 3;

  const int bid = blockIdx.x;
  const int wg = ((bid & 7) << 6) | (bid >> 3);
  const int qt = wg & 15, bh = wg >> 4;
  const int b = bh >> 4, h = bh & 15;
  const int qrow0 = qt * 128 + w4 * 32;

  const u16* qp = Qb + ((size_t)(b * LQ_ + qrow0 + l16)) * 1024 + h * 64;
  s16x8 qf[2][2];
#pragma unroll
  for (int g = 0; g < 2; ++g)
#pragma unroll
    for (int ksq = 0; ksq < 2; ++ksq)
      qf[g][ksq] = *reinterpret_cast<const s16x8*>(qp + g * 16 * 1024 + ksq * 32 + lk * 8);

  f32x4 Oacc[2][4], Osum[2];
#pragma unroll
  for (int g = 0; g < 2; ++g) {
    Osum[g] = (f32x4){0.f, 0.f, 0.f, 0.f};
#pragma unroll
    for (int dt = 0; dt < 4; ++dt) Oacc[g][dt] = (f32x4){0.f, 0.f, 0.f, 0.f};
  }

  const u16* Kg = Kq + ((size_t)(b * LKV_ + half * 1024)) * 1024 + h * 64;
  const u16* Vg = VT + ((size_t)bh * 64) * 2048 + half * 1024;
  char* Kl = smem + half * 32768;
  char* Vl = smem + half * 32768 + 16384;

  s16x8 ones;
#pragma unroll
  for (int i = 0; i < 8; ++i) ones[i] = (short)0x3F80;

  const int r0 = ((l16 >> 2) << 3) + (l16 & 3);
  const int swk = ((l16 & 3) | (((l16 >> 2) & 1) << 2)) << 4;
  const int swv = (l16 & 7) << 4;

  const int srow = (tid & 255) >> 3;
  const int sck = (tid & 7) ^ ((srow & 3) | (((srow >> 3) & 1) << 2));
  const int scv = (tid & 7) ^ (srow & 7);
  const u16* kp0 = Kg + (size_t)srow * 1024 + sck * 8;
  const u16* kp1 = kp0 + (size_t)32 * 1024;
  const u16* vp0 = Vg + (size_t)srow * 2048 + scv * 8;
  const u16* vp1 = vp0 + (size_t)32 * 2048;
  char* kd0 = Kl + w4 * 1024;
  char* vd0 = Vl + w4 * 1024;

  auto stage = [&](int bb) {
    GLOAD(kp0, kd0 + bb * 8192);
    GLOAD(kp1, kd0 + bb * 8192 + 4096);
    GLOAD(vp0, vd0 + bb * 8192);
    GLOAD(vp1, vd0 + bb * 8192 + 4096);
  };

  stage(0);
  kp0 += 65536; kp1 += 65536; vp0 += 64; vp1 += 64;
  __syncthreads();

  int cur = 0;
  for (int jt = 0; jt < 16; ++jt) {
    if (jt < 15) {
      stage(cur ^ 1);
      kp0 += 65536; kp1 += 65536; vp0 += 64; vp1 += 64;
    }
    const char* kb = Kl + cur * 8192;
    const char* vb = Vl + cur * 8192;

    f32x4 sacc[2][4];
#pragma unroll
    for (int g = 0; g < 2; ++g)
#pragma unroll
      for (int ct = 0; ct < 4; ++ct) sacc[g][ct] = (f32x4){0.f, 0.f, 0.f, 0.f};

    __builtin_amdgcn_s_setprio(1);
#pragma unroll
    for (int ct = 0; ct < 4; ++ct) {
      const int R = r0 + ((ct & 1) << 2) + ((ct >> 1) << 5);
      const char* rp = kb + R * 128;
      s16x8 ka0 = *reinterpret_cast<const s16x8*>(rp + ((lk * 16) ^ swk));
      s16x8 ka1 = *reinterpret_cast<const s16x8*>(rp + ((64 + lk * 16) ^ swk));
      sacc[0][ct] = __builtin_amdgcn_mfma_f32_16x16x32_bf16(ka0, qf[0][0], sacc[0][ct], 0, 0, 0);
      sacc[0][ct] = __builtin_amdgcn_mfma_f32_16x16x32_bf16(ka1, qf[0][1], sacc[0][ct], 0, 0, 0);
      sacc[1][ct] = __builtin_amdgcn_mfma_f32_16x16x32_bf16(ka0, qf[1][0], sacc[1][ct], 0, 0, 0);
      sacc[1][ct] = __builtin_amdgcn_mfma_f32_16x16x32_bf16(ka1, qf[1][1], sacc[1][ct], 0, 0, 0);
    }
    __builtin_amdgcn_s_setprio(0);

#pragma unroll
    for (int g = 0; g < 2; ++g)
#pragma unroll
      for (int ct = 0; ct < 4; ++ct)
#pragma unroll
        for (int j = 0; j < 4; ++j)
          sacc[g][ct][j] = fexp2(sacc[g][ct][j]);

#pragma unroll
    for (int f = 0; f < 2; ++f) {
      s16x8 va[4];
#pragma unroll
      for (int dt = 0; dt < 4; ++dt)
        va[dt] = *reinterpret_cast<const s16x8*>(vb + (dt * 16 + l16) * 128 + ((f * 64 + lk * 16) ^ swv));
      s16x8 pf[2];
#pragma unroll
      for (int g = 0; g < 2; ++g) {
        const f32x4 pA = sacc[g][2 * f];
        const f32x4 pB = sacc[g][2 * f + 1];
        union { unsigned u[4]; s16x8 v; } pk;
        pk.u[0] = cvtpk(pA[0], pA[1]);
        pk.u[1] = cvtpk(pA[2], pA[3]);
        pk.u[2] = cvtpk(pB[0], pB[1]);
        pk.u[3] = cvtpk(pB[2], pB[3]);
        pf[g] = pk.v;
      }
      __builtin_amdgcn_s_setprio(1);
#pragma unroll
      for (int dt = 0; dt < 4; ++dt) {
        Oacc[0][dt] = __builtin_amdgcn_mfma_f32_16x16x32_bf16(va[dt], pf[0], Oacc[0][dt], 0, 0, 0);
        Oacc[1][dt] = __builtin_amdgcn_mfma_f32_16x16x32_bf16(va[dt], pf[1], Oacc[1][dt], 0, 0, 0);
      }
      Osum[0] = __builtin_amdgcn_mfma_f32_16x16x32_bf16(ones, pf[0], Osum[0], 0, 0, 0);
      Osum[1] = __builtin_amdgcn_mfma_f32_16x16x32_bf16(ones, pf[1], Osum[1], 0, 0, 0);
      __builtin_amdgcn_s_setprio(0);
    }
    __syncthreads();
    cur ^= 1;
  }

  if (w >= 4) {
    char* mb = smem + (((w - 4) * 64 + l) * 128);
#pragma unroll
    for (int g = 0; g < 2; ++g)
#pragma unroll
      for (int dt = 0; dt < 4; ++dt)
        *reinterpret_cast<f32x4*>(mb + (((g * 4 + dt) * 16) ^ ((l & 7) << 4))) = Oacc[g][dt];
    dmerge[((w - 4) * 64 + l) * 2 + 0] = Osum[0][0];
    dmerge[((w - 4) * 64 + l) * 2 + 1] = Osum[1][0];
  }
  __syncthreads();
  if (w < 4) {
    const char* mb = smem + ((w * 64 + l) * 128);
#pragma unroll
    for (int g = 0; g < 2; ++g) {
      float inv = 1.f / (Osum[g][0] + dmerge[(w * 64 + l) * 2 + g]);
      u16* op = Rb + ((size_t)(b * LQ_ + qrow0 + g * 16 + l16)) * 1024 + h * 64 + lk * 4;
#pragma unroll
      for (int dt = 0; dt < 4; ++dt) {
        f32x4 o2 = *reinterpret_cast<const f32x4*>(mb + (((g * 4 + dt) * 16) ^ ((l & 7) << 4)));
        f32x4 s = Oacc[g][dt] + o2;
        ushort4 o;
        o.x = f2b(s[0] * inv); o.y = f2b(s[1] * inv);
        o.z = f2b(s[2] * inv); o.w = f2b(s[3] * inv);
        *reinterpret_cast<ushort4*>(op + dt * 16) = o;
      }
    }
  }
}

// ---------------- launch ----------------
extern "C" void kernel_launch(void* const* d_in, const int* in_sizes, int n_in,
                              void* d_out, int out_size, void* d_ws, size_t ws_size,
                              hipStream_t stream) {
  const float* x   = (const float*)d_in[0];
  const float* y   = (const float*)d_in[1];
  const float* Wq  = (const float*)d_in[2];
  const float* Wkv = (const float*)d_in[3];
  const float* Wp  = (const float*)d_in[4];
  const float* bp  = (const float*)d_in[5];
  float* out = (float*)d_out;

  u16* p = (u16*)d_ws;
  u16* xb   = p; p += (size_t)4096 * 1024;
  u16* yb   = p; p += (size_t)4096 * 768;
  u16* WqT  = p; p += (size_t)1024 * 1024;
  u16* WkvT = p; p += (size_t)2048 * 768;
  u16* WpT  = p; p += (size_t)1024 * 1024;
  u16* Qb   = p; p += (size_t)4096 * 1024;
  u16* Kbf  = p; p += (size_t)4096 * 1024;   // K compact [b*2048+kv][h*64+d]
  u16* VTb  = p; p += (size_t)4096 * 1024;   // [32][64][2048]
  u16* Rb   = p; p += (size_t)4096 * 1024;

  prep<<<8064, 256, 0, stream>>>(x, xb, y, yb, Wq, WqT, Wkv, WkvT, Wp, WpT);

  // Q = (x @ Wq)*QSCALE and KV = y @ Wkv (K -> Kbf, V -> VTb transposed), one launch
  gemm_qkv<<<1536, 256, 0, stream>>>(xb, WqT, yb, WkvT, Qb, Kbf, VTb);
  // attention -> Rb [4096,1024] (halves merged in-block)
  flash_attn<<<512, 512, 0, stream>>>(Kbf, Qb, VTb, Rb);
  // out = Rb @ Wproj + bias : fp32 [4096,1024]
  gemm_proj<<<512, 256, 0, stream>>>(Rb, WpT, out, bp);
}

// Round 16
// 99.433 us; speedup vs baseline: 1.0565x; 1.0041x over previous
//
#include <hip/hip_runtime.h>
#include <hip/hip_bf16.h>
#include <cstdint>

typedef unsigned short u16;
typedef __attribute__((ext_vector_type(4))) float f32x4;
typedef __attribute__((ext_vector_type(8))) short s16x8;
typedef __attribute__((ext_vector_type(4))) unsigned int u32x4;

#define B_    2
#define LQ_   2048
#define LKV_  2048
#define H_    16
// softmax scale folded into Q at GEMM epilogue: 0.125 * log2(e)
#define QSCALE_ 0.18033688011112042f

__device__ __forceinline__ u16 f2b(float f) {
  union { float f; unsigned int u; } v; v.f = f;
  unsigned int r = v.u + 0x7fffu + ((v.u >> 16) & 1u);
  return (u16)(r >> 16);
}

__device__ __forceinline__ unsigned cvtpk(float lo, float hi) {
  unsigned r;
  asm("v_cvt_pk_bf16_f32 %0, %1, %2" : "=v"(r) : "v"(lo), "v"(hi));
  return r;
}

#if __has_builtin(__builtin_amdgcn_exp2f)
__device__ __forceinline__ float fexp2(float x) { return __builtin_amdgcn_exp2f(x); }
#else
__device__ __forceinline__ float fexp2(float x) {
  float r; asm volatile("v_exp_f32 %0, %1" : "=v"(r) : "v"(x)); return r;
}
#endif

#define GLOAD(g, l) __builtin_amdgcn_global_load_lds( \
    (const __attribute__((address_space(1))) void*)(g), \
    (__attribute__((address_space(3))) void*)(l), 16, 0, 0)

// ---------------- prep: fused input casts + weight transposes ----------------
__global__ void prep(const float* __restrict__ x, u16* __restrict__ xb,
                     const float* __restrict__ y, u16* __restrict__ yb,
                     const float* __restrict__ Wq, u16* __restrict__ WqT,
                     const float* __restrict__ Wkv, u16* __restrict__ WkvT,
                     const float* __restrict__ Wp, u16* __restrict__ WpT) {
  __shared__ u16 tile[64][65];
  const int bid = blockIdx.x;
  const int t = threadIdx.x;
  if (bid < 7168) {
    const float* in; u16* out; int i;
    if (bid < 4096) { in = x; out = xb; i = (bid * 256 + t) * 4; }
    else            { in = y; out = yb; i = ((bid - 4096) * 256 + t) * 4; }
    float4 v = *reinterpret_cast<const float4*>(in + i);
    ushort4 r;
    r.x = f2b(v.x); r.y = f2b(v.y); r.z = f2b(v.z); r.w = f2b(v.w);
    *reinterpret_cast<ushort4*>(out + i) = r;
    return;
  }
  const int tb = bid - 7168;
  const float* W; u16* WT; int K, N, bx, by;
  if (tb < 256)      { W = Wq;  WT = WqT;  K = 1024; N = 1024; bx = tb & 15;         by = tb >> 4; }
  else if (tb < 640) { W = Wkv; WT = WkvT; K = 768;  N = 2048; bx = (tb - 256) & 31; by = (tb - 256) >> 5; }
  else               { W = Wp;  WT = WpT;  K = 1024; N = 1024; bx = (tb - 640) & 15; by = (tb - 640) >> 4; }
  const int n0 = bx * 64, k0 = by * 64;
#pragma unroll
  for (int p = 0; p < 4; ++p) {
    int r = (t >> 4) + p * 16;
    int c = (t & 15) * 4;
    float4 v = *reinterpret_cast<const float4*>(W + (size_t)(k0 + r) * N + n0 + c);
    tile[r][c + 0] = f2b(v.x);
    tile[r][c + 1] = f2b(v.y);
    tile[r][c + 2] = f2b(v.z);
    tile[r][c + 3] = f2b(v.w);
  }
  __syncthreads();
#pragma unroll
  for (int p = 0; p < 4; ++p) {
    int nr = (t >> 4) + p * 16;
    int kc = (t & 15) * 4;
    ushort4 o;
    o.x = tile[kc + 0][nr];
    o.y = tile[kc + 1][nr];
    o.z = tile[kc + 2][nr];
    o.w = tile[kc + 3][nr];
    *reinterpret_cast<ushort4*>(WT + (size_t)(n0 + nr) * K + k0 + kc) = o;
  }
}

// ---------------- GEMM v4 core: 128x64 tile, BK=64, dbuf, 1 barrier/step ----------------
__device__ __forceinline__ void gemm_core(
    int OM, const u16* __restrict__ A, const u16* __restrict__ BT,
    u16* __restrict__ Cb, float* __restrict__ Cf,
    const float* __restrict__ bias, u16* __restrict__ VTp,
    int N, int K, int m0, int n0, char* smem) {
  const int tid = threadIdx.x;
  const int w = tid >> 6, lane = tid & 63;
  const int l16 = lane & 15, lk = lane >> 4;
  const int wm = w >> 1, wn = w & 1;
  const int NS = K >> 6;

  f32x4 acc[4][2];
#pragma unroll
  for (int i = 0; i < 4; ++i)
#pragma unroll
    for (int j = 0; j < 2; ++j)
      acc[i][j] = (f32x4){0.f, 0.f, 0.f, 0.f};

  const int srow = tid >> 3;
  const int sck = (tid & 7) ^ (srow & 7);
  const u16* gA = A + (size_t)(m0 + srow) * K + sck * 8;
  const u16* gB = BT + (size_t)(n0 + srow) * K + sck * 8;
  char* dA = smem + w * 1024;
  char* dB = smem + 32768 + w * 1024;

  auto stage = [&](int k0, int bb) {
#pragma unroll
    for (int i = 0; i < 4; ++i)
      GLOAD(gA + (size_t)i * 32 * K + k0, dA + bb * 16384 + i * 4096);
#pragma unroll
    for (int i = 0; i < 2; ++i)
      GLOAD(gB + (size_t)i * 32 * K + k0, dB + bb * 8192 + i * 4096);
  };

  const int swa = (l16 & 7) << 4;

  stage(0, 0);
  __syncthreads();
  int cur = 0;
  for (int s = 0; s < NS; ++s) {
    if (s + 1 < NS) stage((s + 1) * 64, cur ^ 1);
    const char* sAb = smem + cur * 16384;
    const char* sBb = smem + 32768 + cur * 8192;
#pragma unroll
    for (int kk = 0; kk < 2; ++kk) {
      s16x8 af[4], bf[2];
#pragma unroll
      for (int mt = 0; mt < 4; ++mt)
        af[mt] = *reinterpret_cast<const s16x8*>(
            sAb + (wm * 64 + mt * 16 + l16) * 128 + ((kk * 64 + lk * 16) ^ swa));
#pragma unroll
      for (int nt = 0; nt < 2; ++nt)
        bf[nt] = *reinterpret_cast<const s16x8*>(
            sBb + (wn * 32 + nt * 16 + l16) * 128 + ((kk * 64 + lk * 16) ^ swa));
      __builtin_amdgcn_s_setprio(1);
#pragma unroll
      for (int mt = 0; mt < 4; ++mt)
#pragma unroll
        for (int nt = 0; nt < 2; ++nt)
          acc[mt][nt] = __builtin_amdgcn_mfma_f32_16x16x32_bf16(af[mt], bf[nt], acc[mt][nt], 0, 0, 0);
      __builtin_amdgcn_s_setprio(0);
    }
    __syncthreads();
    cur ^= 1;
  }

#pragma unroll
  for (int mt = 0; mt < 4; ++mt) {
#pragma unroll
    for (int nt = 0; nt < 2; ++nt) {
      const int col = n0 + wn * 32 + nt * 16 + l16;
      const int row0 = m0 + wm * 64 + mt * 16 + lk * 4;
      if (OM == 2 && col >= 1024) {
        int b = row0 >> 11, kv = row0 & 2047;
        int h = (col >> 6) & 15, d = col & 63;
        ushort4 o;
        o.x = f2b(acc[mt][nt][0]); o.y = f2b(acc[mt][nt][1]);
        o.z = f2b(acc[mt][nt][2]); o.w = f2b(acc[mt][nt][3]);
        *reinterpret_cast<ushort4*>(VTp + (((size_t)(b * 16 + h) * 64 + d) * 2048 + kv)) = o;
      } else {
#pragma unroll
        for (int j = 0; j < 4; ++j) {
          int row = row0 + j;
          if (OM == 3)      Cb[(size_t)row * N + col] = f2b(acc[mt][nt][j] * QSCALE_);
          else if (OM == 2) Cb[(size_t)row * 1024 + col] = f2b(acc[mt][nt][j]);
          else              Cf[(size_t)row * N + col] = acc[mt][nt][j] + bias[col];
        }
      }
    }
  }
}

// Q-GEMM (blocks 0..511) + KV-GEMM (blocks 512..1535), natural order (measured best)
__global__ __launch_bounds__(256, 3)
void gemm_qkv(const u16* __restrict__ xb, const u16* __restrict__ WqT,
              const u16* __restrict__ yb, const u16* __restrict__ WkvT,
              u16* __restrict__ Qb, u16* __restrict__ Kbf, u16* __restrict__ VTb) {
  __shared__ __attribute__((aligned(16))) char smem[49152];
  const int bid = blockIdx.x;
  if (bid < 512) {
    gemm_core(3, xb, WqT, Qb, nullptr, nullptr, nullptr,
              1024, 1024, (bid & 31) * 128, (bid >> 5) * 64, smem);
  } else {
    const int t = bid - 512;
    gemm_core(2, yb, WkvT, Kbf, nullptr, nullptr, VTb,
              2048, 768, (t & 31) * 128, (t >> 5) * 64, smem);
  }
}

__global__ __launch_bounds__(256, 3)
void gemm_proj(const u16* __restrict__ Rb, const u16* __restrict__ WpT,
               float* __restrict__ out, const float* __restrict__ bias) {
  __shared__ __attribute__((aligned(16))) char smem[49152];
  const int bid = blockIdx.x;
  gemm_core(1, Rb, WpT, nullptr, out, bias, nullptr,
            1024, 1024, (bid & 31) * 128, (bid >> 5) * 64, smem);
}

// ---------------- flash attention v9: 64 q/wave, 4 waves/block ----------------
// Waves: (w&1)=q-subtile (64 q each), (w>>1)=KV half. 128 q/block, 512 blocks.
// Each ds_read_b128 now feeds 2x the MFMA of v8 (16 reads -> 72 MFMA/step/wave):
// per-CU LDS wave-instructions halve (the v8 bottleneck).
// All fragment math (R perm, swk/swv swizzles, PV pack, ones-MFMA) identical to v8.
__global__ __launch_bounds__(256, 2)
void flash_attn(const u16* __restrict__ Kq, const u16* __restrict__ Qb,
                const u16* __restrict__ VT, u16* __restrict__ Rb) {
  __shared__ __attribute__((aligned(16))) char smem[65536];
  __shared__ float dmerge[640];   // [2 qsub][64 lanes] stride 5 (bank-conflict-free)

  const int tid = threadIdx.x;
  const int w = tid >> 6, l = tid & 63;
  const int l16 = l & 15, lk = l >> 4;
  const int half = w >> 1, qs = w & 1;

  // bijective XCD swizzle: 512 blocks = 8 x 64
  const int bid = blockIdx.x;
  const int wg = ((bid & 7) << 6) | (bid >> 3);
  const int qt = wg & 15, bh = wg >> 4;
  const int b = bh >> 4, h = bh & 15;
  const int qrow0 = qt * 128 + qs * 64;

  // Q B-fragments: 4 groups of 16 q
  const u16* qp = Qb + ((size_t)(b * LQ_ + qrow0 + l16)) * 1024 + h * 64;
  s16x8 qf[4][2];
#pragma unroll
  for (int g = 0; g < 4; ++g)
#pragma unroll
    for (int ksq = 0; ksq < 2; ++ksq)
      qf[g][ksq] = *reinterpret_cast<const s16x8*>(qp + g * 16 * 1024 + ksq * 32 + lk * 8);

  f32x4 Oacc[4][4], Osum[4];
#pragma unroll
  for (int g = 0; g < 4; ++g) {
    Osum[g] = (f32x4){0.f, 0.f, 0.f, 0.f};
#pragma unroll
    for (int dt = 0; dt < 4; ++dt) Oacc[g][dt] = (f32x4){0.f, 0.f, 0.f, 0.f};
  }

  const u16* Kg = Kq + ((size_t)(b * LKV_ + half * 1024)) * 1024 + h * 64;
  const u16* Vg = VT + ((size_t)bh * 64) * 2048 + half * 1024;
  char* Kl = smem + half * 32768;
  char* Vl = smem + half * 32768 + 16384;

  s16x8 ones;
#pragma unroll
  for (int i = 0; i < 8; ++i) ones[i] = (short)0x3F80;

  const int r0 = ((l16 >> 2) << 3) + (l16 & 3);
  const int swk = ((l16 & 3) | (((l16 >> 2) & 1) << 2)) << 4;
  const int swv = (l16 & 7) << 4;

  // staging: half's 128 threads, 4 rounds of 16 rows (16B/thread/round).
  // srow in 0..15; covered rows srow+16i; source pre-XOR proven round-invariant:
  // (row&3)=srow&3, ((row>>3)&1)=((srow>>3)&1), (row&7)=srow&7.
  const int ht = tid & 127;
  const int srow = ht >> 3;
  const int c8 = ht & 7;
  const int sck = c8 ^ ((srow & 3) | (((srow >> 3) & 1) << 2));
  const int scv = c8 ^ (srow & 7);
  const u16* kp = Kg + (size_t)srow * 1024 + sck * 8;
  const u16* vp = Vg + (size_t)srow * 2048 + scv * 8;
  char* kd = Kl + qs * 1024;   // + bb*8192 + i*2048 ; lane*16 implicit
  char* vd = Vl + qs * 1024;

  auto stage = [&](int bb) {
#pragma unroll
    for (int i = 0; i < 4; ++i) {
      GLOAD(kp + (size_t)(16 * i) * 1024, kd + bb * 8192 + i * 2048);
      GLOAD(vp + (size_t)(16 * i) * 2048, vd + bb * 8192 + i * 2048);
    }
  };

  stage(0);
  kp += 65536; vp += 64;
  __syncthreads();

  int cur = 0;
  for (int jt = 0; jt < 16; ++jt) {
    if (jt < 15) {
      stage(cur ^ 1);
      kp += 65536; vp += 64;
    }
    const char* kb = Kl + cur * 8192;
    const char* vb = Vl + cur * 8192;

    // ---- S^T = K_perm . Q^T (exp2 domain, no max) ----
    f32x4 sacc[4][4];
#pragma unroll
    for (int g = 0; g < 4; ++g)
#pragma unroll
      for (int ct = 0; ct < 4; ++ct) sacc[g][ct] = (f32x4){0.f, 0.f, 0.f, 0.f};

    __builtin_amdgcn_s_setprio(1);
#pragma unroll
    for (int ct = 0; ct < 4; ++ct) {
      const int R = r0 + ((ct & 1) << 2) + ((ct >> 1) << 5);
      const char* rp = kb + R * 128;
      s16x8 ka0 = *reinterpret_cast<const s16x8*>(rp + ((lk * 16) ^ swk));
      s16x8 ka1 = *reinterpret_cast<const s16x8*>(rp + ((64 + lk * 16) ^ swk));
#pragma unroll
      for (int g = 0; g < 4; ++g) {
        sacc[g][ct] = __builtin_amdgcn_mfma_f32_16x16x32_bf16(ka0, qf[g][0], sacc[g][ct], 0, 0, 0);
        sacc[g][ct] = __builtin_amdgcn_mfma_f32_16x16x32_bf16(ka1, qf[g][1], sacc[g][ct], 0, 0, 0);
      }
    }
    __builtin_amdgcn_s_setprio(0);

    // ---- P = exp2(S) in-register ----
#pragma unroll
    for (int g = 0; g < 4; ++g)
#pragma unroll
      for (int ct = 0; ct < 4; ++ct)
#pragma unroll
        for (int j = 0; j < 4; ++j)
          sacc[g][ct][j] = fexp2(sacc[g][ct][j]);

    // ---- O^T += VT . P^T ; denominator += ones . P^T ----
#pragma unroll
    for (int f = 0; f < 2; ++f) {
      s16x8 va[4];
#pragma unroll
      for (int dt = 0; dt < 4; ++dt)
        va[dt] = *reinterpret_cast<const s16x8*>(vb + (dt * 16 + l16) * 128 + ((f * 64 + lk * 16) ^ swv));
      s16x8 pf[4];
#pragma unroll
      for (int g = 0; g < 4; ++g) {
        const f32x4 pA = sacc[g][2 * f];
        const f32x4 pB = sacc[g][2 * f + 1];
        union { unsigned u[4]; s16x8 v; } pk;
        pk.u[0] = cvtpk(pA[0], pA[1]);
        pk.u[1] = cvtpk(pA[2], pA[3]);
        pk.u[2] = cvtpk(pB[0], pB[1]);
        pk.u[3] = cvtpk(pB[2], pB[3]);
        pf[g] = pk.v;
      }
      __builtin_amdgcn_s_setprio(1);
#pragma unroll
      for (int dt = 0; dt < 4; ++dt)
#pragma unroll
        for (int g = 0; g < 4; ++g)
          Oacc[g][dt] = __builtin_amdgcn_mfma_f32_16x16x32_bf16(va[dt], pf[g], Oacc[g][dt], 0, 0, 0);
#pragma unroll
      for (int g = 0; g < 4; ++g)
        Osum[g] = __builtin_amdgcn_mfma_f32_16x16x32_bf16(ones, pf[g], Osum[g], 0, 0, 0);
      __builtin_amdgcn_s_setprio(0);
    }
    __syncthreads();
    cur ^= 1;
  }

  // ---- merge halves through LDS (half-0 staging region, now dead) ----
  if (half == 1) {
    char* mb = smem + qs * 16384 + l * 256;
#pragma unroll
    for (int g = 0; g < 4; ++g)
#pragma unroll
      for (int dt = 0; dt < 4; ++dt)
        *reinterpret_cast<f32x4*>(mb + (((g * 4 + dt) * 16) ^ ((l & 7) << 4))) = Oacc[g][dt];
#pragma unroll
    for (int g = 0; g < 4; ++g)
      dmerge[(qs * 64 + l) * 5 + g] = Osum[g][0];
  }
  __syncthreads();
  if (half == 0) {
    const char* mb = smem + qs * 16384 + l * 256;
#pragma unroll
    for (int g = 0; g < 4; ++g) {
      float inv = 1.f / (Osum[g][0] + dmerge[(qs * 64 + l) * 5 + g]);
      u16* op = Rb + ((size_t)(b * LQ_ + qrow0 + g * 16 + l16)) * 1024 + h * 64 + lk * 4;
#pragma unroll
      for (int dt = 0; dt < 4; ++dt) {
        f32x4 o2 = *reinterpret_cast<const f32x4*>(mb + (((g * 4 + dt) * 16) ^ ((l & 7) << 4)));
        f32x4 s = Oacc[g][dt] + o2;
        ushort4 o;
        o.x = f2b(s[0] * inv); o.y = f2b(s[1] * inv);
        o.z = f2b(s[2] * inv); o.w = f2b(s[3] * inv);
        *reinterpret_cast<ushort4*>(op + dt * 16) = o;
      }
    }
  }
}

// ---------------- launch ----------------
extern "C" void kernel_launch(void* const* d_in, const int* in_sizes, int n_in,
                              void* d_out, int out_size, void* d_ws, size_t ws_size,
                              hipStream_t stream) {
  const float* x   = (const float*)d_in[0];
  const float* y   = (const float*)d_in[1];
  const float* Wq  = (const float*)d_in[2];
  const float* Wkv = (const float*)d_in[3];
  const float* Wp  = (const float*)d_in[4];
  const float* bp  = (const float*)d_in[5];
  float* out = (float*)d_out;

  u16* p = (u16*)d_ws;
  u16* xb   = p; p += (size_t)4096 * 1024;
  u16* yb   = p; p += (size_t)4096 * 768;
  u16* WqT  = p; p += (size_t)1024 * 1024;
  u16* WkvT = p; p += (size_t)2048 * 768;
  u16* WpT  = p; p += (size_t)1024 * 1024;
  u16* Qb   = p; p += (size_t)4096 * 1024;
  u16* Kbf  = p; p += (size_t)4096 * 1024;   // K compact [b*2048+kv][h*64+d]
  u16* VTb  = p; p += (size_t)4096 * 1024;   // [32][64][2048]
  u16* Rb   = p; p += (size_t)4096 * 1024;

  prep<<<8064, 256, 0, stream>>>(x, xb, y, yb, Wq, WqT, Wkv, WkvT, Wp, WpT);

  // Q = (x @ Wq)*QSCALE and KV = y @ Wkv (K -> Kbf, V -> VTb transposed), one launch
  gemm_qkv<<<1536, 256, 0, stream>>>(xb, WqT, yb, WkvT, Qb, Kbf, VTb);
  // attention -> Rb [4096,1024] (halves merged in-block)
  flash_attn<<<512, 256, 0, stream>>>(Kbf, Qb, VTb, Rb);
  // out = Rb @ Wproj + bias : fp32 [4096,1024]
  gemm_proj<<<512, 256, 0, stream>>>(Rb, WpT, out, bp);
}